// Round 6
// baseline (1013.668 us; speedup 1.0000x reference)
//
#include <hip/hip_runtime.h>
#include <hip/hip_bf16.h>

// GNN: node_proj + edge scatter_mean/proj -> concat -> GAT(512->4x64) -> ELU
//      -> GAT(256->4x64) -> ELU -> out_proj. ALL tensors float32 (per ref).
// R5: (a) single-pass agg (fused denom, no max-subtract; unroll-2 -> 8 edges
//     in flight/block). (b) GEMM full 256-col blocks: A re-read halved,
//     fused att-dots stored directly (no atomics, no memsets).

#define HEADS 4

typedef __attribute__((ext_vector_type(8))) short bf16x8;
typedef __attribute__((ext_vector_type(4))) float f32x4;

__device__ __forceinline__ unsigned short f2b(float v) {
    __hip_bfloat16 b = __float2bfloat16(v);
    return __builtin_bit_cast(unsigned short, b);
}
__device__ __forceinline__ float b2f(unsigned short u) {
    __hip_bfloat16 b = __builtin_bit_cast(__hip_bfloat16, u);
    return __bfloat162float(b);
}
__device__ __forceinline__ void split_hilo(float v, unsigned short& h, unsigned short& l) {
    h = f2b(v);
    l = f2b(v - b2f(h));
}

// ============================ CSR construction =============================

__global__ __launch_bounds__(256) void count_kernel(
    const int* __restrict__ dst, int* __restrict__ cnt, int E)
{
    int e = blockIdx.x * 256 + threadIdx.x;
    if (e < E) atomicAdd(&cnt[dst[e]], 1);
}

__global__ __launch_bounds__(256) void scan1_kernel(
    const int* __restrict__ cnt, int* __restrict__ chunk_sum, int N)
{
    __shared__ int sd[256];
    int t = threadIdx.x;
    int n = blockIdx.x * 256 + t;
    sd[t] = (n < N) ? (cnt[n] + 1) : 0;
    __syncthreads();
    for (int o = 128; o > 0; o >>= 1) {
        if (t < o) sd[t] += sd[t + o];
        __syncthreads();
    }
    if (t == 0) chunk_sum[blockIdx.x] = sd[0];
}

__global__ void scan2_kernel(const int* __restrict__ chunk_sum,
                             int* __restrict__ chunk_off, int nchunk)
{
    int acc = 0;
    for (int i = 0; i < nchunk; i++) {
        chunk_off[i] = acc;
        acc += chunk_sum[i];
    }
}

__global__ __launch_bounds__(256) void scan3_kernel(
    const int* __restrict__ cnt, const int* __restrict__ chunk_off,
    int* __restrict__ rowptr, int* __restrict__ fillptr,
    int* __restrict__ col, int* __restrict__ eid, int N)
{
    __shared__ int sd[256];
    int t = threadIdx.x;
    int n = blockIdx.x * 256 + t;
    int v = (n < N) ? (cnt[n] + 1) : 0;
    sd[t] = v;
    __syncthreads();
    for (int o = 1; o < 256; o <<= 1) {
        int x = (t >= o) ? sd[t - o] : 0;
        __syncthreads();
        sd[t] += x;
        __syncthreads();
    }
    if (n < N) {
        int incl = sd[t];
        int r = chunk_off[blockIdx.x] + incl - v;
        rowptr[n] = r;
        col[r] = n;        // self loop, first entry
        eid[r] = -1;
        fillptr[n] = r + 1;
        if (n == N - 1) rowptr[N] = chunk_off[blockIdx.x] + incl;
    }
}

__global__ __launch_bounds__(256) void fill_kernel(
    const int* __restrict__ src, const int* __restrict__ dst,
    int* __restrict__ fillptr, int* __restrict__ col, int* __restrict__ eid, int E)
{
    int e = blockIdx.x * 256 + threadIdx.x;
    if (e >= E) return;
    int d = dst[e];
    int p = atomicAdd(&fillptr[d], 1);
    col[p] = src[e];
    eid[p] = e;
}

// ====== edge_attr scatter-mean via CSR -> hi/lo bf16 [N x 32] (K-padded) ===
__global__ __launch_bounds__(64) void nef_csr_kernel(
    const float* __restrict__ ea, const int* __restrict__ rowptr,
    const int* __restrict__ eid,
    unsigned short* __restrict__ nefH, unsigned short* __restrict__ nefL, int N)
{
    int n = blockIdx.x;
    int t = threadIdx.x;
    int f = t & 15, g = t >> 4;
    int base = rowptr[n], end = rowptr[n + 1];
    int deg = end - base - 1;
    float acc = 0.0f;
    for (int j = base + 1 + g; j < end; j += 4) {
        int e = eid[j];
        acc += ea[(size_t)e * 16 + f];
    }
    acc += __shfl_down(acc, 32, 64);
    acc += __shfl_down(acc, 16, 64);
    if (t < 16) {
        float v = acc / fmaxf((float)deg, 1.0f);
        unsigned short h, l;
        split_hilo(v, h, l);
        nefH[(size_t)n * 32 + t] = h;
        nefL[(size_t)n * 32 + t] = l;
    } else if (t < 32) {
        nefH[(size_t)n * 32 + t] = 0;
        nefL[(size_t)n * 32 + t] = 0;
    }
}

// ============ convert f32 -> hi/lo bf16 (2 elems per thread) ===============
__global__ __launch_bounds__(256) void conv_hilo_kernel(
    const float* __restrict__ X,
    unsigned short* __restrict__ H, unsigned short* __restrict__ L, int total)
{
    int base = (blockIdx.x * 256 + threadIdx.x) * 2;
    if (base >= total) return;
    #pragma unroll
    for (int i = 0; i < 2; i++) {
        unsigned short h, l;
        split_hilo(X[base + i], h, l);
        H[base + i] = h;
        L[base + i] = l;
    }
}

// ============ pack weights [K x 256] -> B-fragment order, hi/lo ============
__global__ __launch_bounds__(256) void pack_w_kernel(
    const float* __restrict__ W, int K, int KP,
    unsigned short* __restrict__ Ph, unsigned short* __restrict__ Pl)
{
    int idx = blockIdx.x * 256 + threadIdx.x;
    if (idx >= KP * 256) return;
    int tile = idx >> 9, w = idx & 511, lane = w >> 3, j = w & 7;
    int nk = KP >> 5;
    int ctile = tile / nk, t = tile % nk;
    int k = t * 32 + ((lane >> 4) << 3) + j;
    int n = (ctile << 4) + (lane & 15);
    float v = (k < K) ? W[(size_t)k * 256 + n] : 0.0f;
    unsigned short h, l;
    split_hilo(v, h, l);
    Ph[idx] = h;
    Pl[idx] = l;
}

// ===================== MFMA bf16x3 GEMM ====================================
// C[N x 256] = A[N x KP] @ W[KP x 256] (+bias). Block: 64 rows x 256 cols,
// 4 waves (wave = 16 rows), 16 col-tiles. FUSE_ATT: per-row per-head
// attention dots from accumulators, direct store (full row in-block).
template <int KSTEPS, bool HILO, bool FUSE_ATT>
__global__ __launch_bounds__(256) void mfma_gemm_kernel(
    const unsigned short* __restrict__ Ah, const unsigned short* __restrict__ Al,
    int lda,
    const unsigned short* __restrict__ Ph, const unsigned short* __restrict__ Pl,
    const float* __restrict__ bias,
    float* __restrict__ Cf,
    unsigned short* __restrict__ Ch, unsigned short* __restrict__ Cl,
    int ldc, int col_off, int Nrows,
    const float* __restrict__ att_src, const float* __restrict__ att_dst,
    float* __restrict__ a_srcO, float* __restrict__ a_dstO)
{
    int tid = threadIdx.x;
    int wave = tid >> 6, lane = tid & 63;
    int quad = lane >> 4, m16 = lane & 15;
    int row = blockIdx.x * 64 + wave * 16 + m16;
    bool rowok = row < Nrows;

    f32x4 acc[16] = {};
    const unsigned short* arh = Ah + (size_t)row * lda;
    const unsigned short* arl = Al + (size_t)row * lda;

    for (int t = 0; t < KSTEPS; t++) {
        int k = t * 32 + quad * 8;
        bf16x8 a_h = {}, a_l = {};
        if (rowok) {
            a_h = *(const bf16x8*)(arh + k);
            a_l = *(const bf16x8*)(arl + k);
        }
        #pragma unroll
        for (int c = 0; c < 16; c++) {
            size_t wb = ((size_t)(c * KSTEPS + t)) * 512 + lane * 8;
            bf16x8 b_h = *(const bf16x8*)(Ph + wb);
            bf16x8 b_l = *(const bf16x8*)(Pl + wb);
            acc[c] = __builtin_amdgcn_mfma_f32_16x16x32_bf16(a_h, b_h, acc[c], 0, 0, 0);
            acc[c] = __builtin_amdgcn_mfma_f32_16x16x32_bf16(a_l, b_h, acc[c], 0, 0, 0);
            acc[c] = __builtin_amdgcn_mfma_f32_16x16x32_bf16(a_h, b_l, acc[c], 0, 0, 0);
        }
    }

    // main epilogue: D[row = quad*4 + r][col = m16] within each 16x16 tile
    #pragma unroll
    for (int c = 0; c < 16; c++) {
        int ocol = c * 16 + m16;
        float bv = bias ? bias[ocol] : 0.0f;
        #pragma unroll
        for (int r = 0; r < 4; r++) {
            int orow = blockIdx.x * 64 + wave * 16 + quad * 4 + r;
            if (orow >= Nrows) continue;
            float v = acc[c][r] + bv;
            size_t oidx = (size_t)orow * ldc + col_off + ocol;
            if (HILO) {
                unsigned short h, l;
                split_hilo(v, h, l);
                Ch[oidx] = h;
                Cl[oidx] = l;
            } else {
                Cf[oidx] = v;
            }
        }
    }

    if (FUSE_ATT) {
        // per-row (r), per-head (h = c>>2) attention dot partials
        float ps[4][4] = {}, pd[4][4] = {};
        #pragma unroll
        for (int c = 0; c < 16; c++) {
            int ocol = c * 16 + m16;
            float asv = att_src[ocol];
            float adv = att_dst[ocol];
            int h = c >> 2;
            #pragma unroll
            for (int r = 0; r < 4; r++) {
                ps[r][h] += acc[c][r] * asv;
                pd[r][h] += acc[c][r] * adv;
            }
        }
        #pragma unroll
        for (int r = 0; r < 4; r++) {
            #pragma unroll
            for (int h = 0; h < 4; h++) {
                float s = ps[r][h], d = pd[r][h];
                #pragma unroll
                for (int o = 8; o > 0; o >>= 1) {
                    s += __shfl_down(s, o, 64);
                    d += __shfl_down(d, o, 64);
                }
                if (m16 == 0) {
                    int orow = blockIdx.x * 64 + wave * 16 + quad * 4 + r;
                    if (orow < Nrows) {
                        a_srcO[orow * 4 + h] = s;
                        a_dstO[orow * 4 + h] = d;
                    }
                }
            }
        }
    }
}

// ===== CSR aggregation: single-pass softmax + weighted sum + bias + ELU ====
// one block per dst node; 4 groups (waves) x unroll-2 = 8 edges in flight;
// lane covers 4 consecutive cols via float4; unnormalized accumulation with
// fused denominator (no max-subtract: logits O(10), exp safe in f32).
__global__ __launch_bounds__(256) void gat_agg_csr_kernel(
    const float* __restrict__ xh,
    const int* __restrict__ rowptr, const int* __restrict__ col,
    const float* __restrict__ a_src, const float* __restrict__ a_dst,
    const float* __restrict__ bias,
    unsigned short* __restrict__ outH, unsigned short* __restrict__ outL, int N)
{
    __shared__ float red[1024];
    __shared__ float dpart[4][HEADS];
    int n = blockIdx.x;
    int t = threadIdx.x;
    int g = t >> 6, c = t & 63;
    int h = c >> 4;
    int base = rowptr[n], end = rowptr[n + 1];
    float adst = a_dst[n * 4 + h];
    const float* xcol = xh + (c << 2);

    float4 acc = {0.0f, 0.0f, 0.0f, 0.0f};
    float den = 0.0f;
    int j = base + 2 * g;
    for (; j + 1 < end; j += 8) {
        int s0 = col[j], s1 = col[j + 1];
        float l0 = a_src[s0 * 4 + h] + adst;
        float l1 = a_src[s1 * 4 + h] + adst;
        l0 = (l0 > 0.0f) ? l0 : 0.2f * l0;
        l1 = (l1 > 0.0f) ? l1 : 0.2f * l1;
        float w0 = __expf(l0), w1 = __expf(l1);
        float4 x0 = *(const float4*)(xcol + (size_t)s0 * 256);
        float4 x1 = *(const float4*)(xcol + (size_t)s1 * 256);
        den += w0 + w1;
        acc.x += w0 * x0.x + w1 * x1.x;
        acc.y += w0 * x0.y + w1 * x1.y;
        acc.z += w0 * x0.z + w1 * x1.z;
        acc.w += w0 * x0.w + w1 * x1.w;
    }
    if (j < end) {
        int s0 = col[j];
        float l0 = a_src[s0 * 4 + h] + adst;
        l0 = (l0 > 0.0f) ? l0 : 0.2f * l0;
        float w0 = __expf(l0);
        float4 x0 = *(const float4*)(xcol + (size_t)s0 * 256);
        den += w0;
        acc.x += w0 * x0.x;
        acc.y += w0 * x0.y;
        acc.z += w0 * x0.z;
        acc.w += w0 * x0.w;
    }
    *(float4*)(&red[g * 256 + (c << 2)]) = acc;
    if ((c & 15) == 0) dpart[g][h] = den;
    __syncthreads();

    // combine groups + normalize + bias + ELU + hi/lo split; thread t = col t
    int th = t >> 6;
    float dsum = dpart[0][th] + dpart[1][th] + dpart[2][th] + dpart[3][th];
    float v = (red[t] + red[256 + t] + red[512 + t] + red[768 + t]) / dsum + bias[t];
    v = (v > 0.0f) ? v : (__expf(v) - 1.0f);
    unsigned short hh, ll;
    split_hilo(v, hh, ll);
    outH[(size_t)n * 256 + t] = hh;
    outL[(size_t)n * 256 + t] = ll;
}

// ===========================================================================

extern "C" void kernel_launch(void* const* d_in, const int* in_sizes, int n_in,
                              void* d_out, int out_size, void* d_ws, size_t ws_size,
                              hipStream_t stream)
{
    const float* node_feats = (const float*)d_in[0];
    const float* edge_attr  = (const float*)d_in[1];
    const float* Wnp = (const float*)d_in[2];
    const float* bnp = (const float*)d_in[3];
    const float* Wep = (const float*)d_in[4];
    const float* bep = (const float*)d_in[5];
    const float* Wg1 = (const float*)d_in[6];
    const float* as1 = (const float*)d_in[7];
    const float* ad1 = (const float*)d_in[8];
    const float* bg1 = (const float*)d_in[9];
    const float* Wg2 = (const float*)d_in[10];
    const float* as2 = (const float*)d_in[11];
    const float* ad2 = (const float*)d_in[12];
    const float* bg2 = (const float*)d_in[13];
    const float* Wo  = (const float*)d_in[14];
    const float* bo  = (const float*)d_in[15];
    const int*   ei  = (const int*)d_in[16];

    const int N = in_sizes[0] / 128;   // 50000
    const int E = in_sizes[16] / 2;    // 800000
    const int* src = ei;
    const int* dst = ei + E;
    const int nchunk = (N + 255) / 256;
    const int EN = E + N;

    typedef unsigned short u16;

    // ---- workspace layout (256B-aligned regions) ----
    char* base = (char*)d_ws;
    size_t off = 0;
    auto alloc = [&](size_t bytes) -> char* {
        char* p = base + off;
        off += (bytes + 255) & ~(size_t)255;
        return p;
    };
    float* xh = (float*)alloc((size_t)N * 256 * 4);        // f32 xh; hosts nf/nef aliases
    u16* x2H  = (u16*)alloc((size_t)N * 512 * 2);          // hosts x3H/x3L after GEMM3
    u16* x2L  = (u16*)alloc((size_t)N * 512 * 2);          // hosts x4H/x4L after GEMM3
    float* a_src = (float*)alloc((size_t)N * 4 * 4);
    float* a_dst = (float*)alloc((size_t)N * 4 * 4);
    u16* PnpH = (u16*)alloc(128 * 256 * 2);
    u16* PnpL = (u16*)alloc(128 * 256 * 2);
    u16* PepH = (u16*)alloc(32 * 256 * 2);
    u16* PepL = (u16*)alloc(32 * 256 * 2);
    u16* Pg1H = (u16*)alloc(512 * 256 * 2);
    u16* Pg1L = (u16*)alloc(512 * 256 * 2);
    u16* Pg2H = (u16*)alloc(256 * 256 * 2);
    u16* Pg2L = (u16*)alloc(256 * 256 * 2);
    u16* PoH  = (u16*)alloc(256 * 256 * 2);
    u16* PoL  = (u16*)alloc(256 * 256 * 2);
    int* cnt       = (int*)alloc((size_t)N * 4);
    int* rowptr    = (int*)alloc((size_t)(N + 1) * 4);
    int* fillptr   = (int*)alloc((size_t)N * 4);
    int* chunk_sum = (int*)alloc((size_t)nchunk * 4);
    int* chunk_off = (int*)alloc((size_t)nchunk * 4);
    int* colv      = (int*)alloc((size_t)EN * 4);
    int* eid       = (int*)alloc((size_t)EN * 4);

    // aliases inside xh region (dead before GEMM3 writes xh)
    u16* nfH  = (u16*)xh;
    u16* nfL  = nfH + (size_t)N * 128;
    u16* nefH = nfL + (size_t)N * 128;
    u16* nefL = nefH + (size_t)N * 32;
    // aliases inside x2 regions (x2 dead after GEMM3)
    u16* x3H = x2H;
    u16* x3L = x2H + (size_t)N * 256;
    u16* x4H = x2L;
    u16* x4L = x2L + (size_t)N * 256;

    float* out = (float*)d_out;
    dim3 ggrid((N + 63) / 64);

    // ---- CSR build ----
    hipMemsetAsync(cnt, 0, (size_t)N * sizeof(int), stream);
    count_kernel<<<(E + 255) / 256, 256, 0, stream>>>(dst, cnt, E);
    scan1_kernel<<<nchunk, 256, 0, stream>>>(cnt, chunk_sum, N);
    scan2_kernel<<<1, 1, 0, stream>>>(chunk_sum, chunk_off, nchunk);
    scan3_kernel<<<nchunk, 256, 0, stream>>>(cnt, chunk_off, rowptr, fillptr, colv, eid, N);
    fill_kernel<<<(E + 255) / 256, 256, 0, stream>>>(src, dst, fillptr, colv, eid, E);

    // ---- input conversions + weight packing ----
    nef_csr_kernel<<<N, 64, 0, stream>>>(edge_attr, rowptr, eid, nefH, nefL, N);
    conv_hilo_kernel<<<((N * 128) / 2 + 255) / 256, 256, 0, stream>>>(
        node_feats, nfH, nfL, N * 128);
    pack_w_kernel<<<(128 * 256 + 255) / 256, 256, 0, stream>>>(Wnp, 128, 128, PnpH, PnpL);
    pack_w_kernel<<<(32 * 256 + 255) / 256, 256, 0, stream>>>(Wep, 16, 32, PepH, PepL);
    pack_w_kernel<<<(512 * 256 + 255) / 256, 256, 0, stream>>>(Wg1, 512, 512, Pg1H, Pg1L);
    pack_w_kernel<<<(256 * 256 + 255) / 256, 256, 0, stream>>>(Wg2, 256, 256, Pg2H, Pg2L);
    pack_w_kernel<<<(256 * 256 + 255) / 256, 256, 0, stream>>>(Wo, 256, 256, PoH, PoL);

    // ---- x2 = [ nf@Wnp + bnp | nef@Wep + bep ] -> x2H/x2L [N x 512] ----
    mfma_gemm_kernel<4, true, false><<<ggrid, 256, 0, stream>>>(
        nfH, nfL, 128, PnpH, PnpL, bnp, nullptr, x2H, x2L, 512, 0, N,
        nullptr, nullptr, nullptr, nullptr);
    mfma_gemm_kernel<1, true, false><<<ggrid, 256, 0, stream>>>(
        nefH, nefL, 32, PepH, PepL, bep, nullptr, x2H, x2L, 512, 256, N,
        nullptr, nullptr, nullptr, nullptr);

    // ---- GAT layer 1: GEMM (+fused att dots) -> agg ----
    mfma_gemm_kernel<16, false, true><<<ggrid, 256, 0, stream>>>(
        x2H, x2L, 512, Pg1H, Pg1L, nullptr, xh, nullptr, nullptr, 256, 0, N,
        as1, ad1, a_src, a_dst);
    gat_agg_csr_kernel<<<N, 256, 0, stream>>>(
        xh, rowptr, colv, a_src, a_dst, bg1, x3H, x3L, N);

    // ---- GAT layer 2 ----
    mfma_gemm_kernel<8, false, true><<<ggrid, 256, 0, stream>>>(
        x3H, x3L, 256, Pg2H, Pg2L, nullptr, xh, nullptr, nullptr, 256, 0, N,
        as2, ad2, a_src, a_dst);
    gat_agg_csr_kernel<<<N, 256, 0, stream>>>(
        xh, rowptr, colv, a_src, a_dst, bg2, x4H, x4L, N);

    // ---- out = x4 @ Wo + bo -> d_out (f32) ----
    mfma_gemm_kernel<8, false, false><<<ggrid, 256, 0, stream>>>(
        x4H, x4L, 256, PoH, PoL, bo, out, nullptr, nullptr, 256, 0, N,
        nullptr, nullptr, nullptr, nullptr);
}

// Round 7
// 830.236 us; speedup vs baseline: 1.2209x; 1.2209x over previous
//
#include <hip/hip_runtime.h>
#include <hip/hip_bf16.h>

// GNN: node_proj + edge scatter_mean/proj -> concat -> GAT(512->4x64) -> ELU
//      -> GAT(256->4x64) -> ELU -> out_proj. ALL tensors float32 (per ref).
// R6: GEMM reverted to 64x128 blocks (grid.y=2, acc[8] — R6's 256-col blocks
//     tanked occupancy to 18%). Fused att-dots stay direct-store (each block
//     wholly contains heads 2y,2y+1). Single-pass agg kept from R5.

#define HEADS 4

typedef __attribute__((ext_vector_type(8))) short bf16x8;
typedef __attribute__((ext_vector_type(4))) float f32x4;

__device__ __forceinline__ unsigned short f2b(float v) {
    __hip_bfloat16 b = __float2bfloat16(v);
    return __builtin_bit_cast(unsigned short, b);
}
__device__ __forceinline__ float b2f(unsigned short u) {
    __hip_bfloat16 b = __builtin_bit_cast(__hip_bfloat16, u);
    return __bfloat162float(b);
}
__device__ __forceinline__ void split_hilo(float v, unsigned short& h, unsigned short& l) {
    h = f2b(v);
    l = f2b(v - b2f(h));
}

// ============================ CSR construction =============================

__global__ __launch_bounds__(256) void count_kernel(
    const int* __restrict__ dst, int* __restrict__ cnt, int E)
{
    int e = blockIdx.x * 256 + threadIdx.x;
    if (e < E) atomicAdd(&cnt[dst[e]], 1);
}

__global__ __launch_bounds__(256) void scan1_kernel(
    const int* __restrict__ cnt, int* __restrict__ chunk_sum, int N)
{
    __shared__ int sd[256];
    int t = threadIdx.x;
    int n = blockIdx.x * 256 + t;
    sd[t] = (n < N) ? (cnt[n] + 1) : 0;
    __syncthreads();
    for (int o = 128; o > 0; o >>= 1) {
        if (t < o) sd[t] += sd[t + o];
        __syncthreads();
    }
    if (t == 0) chunk_sum[blockIdx.x] = sd[0];
}

__global__ void scan2_kernel(const int* __restrict__ chunk_sum,
                             int* __restrict__ chunk_off, int nchunk)
{
    int acc = 0;
    for (int i = 0; i < nchunk; i++) {
        chunk_off[i] = acc;
        acc += chunk_sum[i];
    }
}

__global__ __launch_bounds__(256) void scan3_kernel(
    const int* __restrict__ cnt, const int* __restrict__ chunk_off,
    int* __restrict__ rowptr, int* __restrict__ fillptr,
    int* __restrict__ col, int* __restrict__ eid, int N)
{
    __shared__ int sd[256];
    int t = threadIdx.x;
    int n = blockIdx.x * 256 + t;
    int v = (n < N) ? (cnt[n] + 1) : 0;
    sd[t] = v;
    __syncthreads();
    for (int o = 1; o < 256; o <<= 1) {
        int x = (t >= o) ? sd[t - o] : 0;
        __syncthreads();
        sd[t] += x;
        __syncthreads();
    }
    if (n < N) {
        int incl = sd[t];
        int r = chunk_off[blockIdx.x] + incl - v;
        rowptr[n] = r;
        col[r] = n;        // self loop, first entry
        eid[r] = -1;
        fillptr[n] = r + 1;
        if (n == N - 1) rowptr[N] = chunk_off[blockIdx.x] + incl;
    }
}

__global__ __launch_bounds__(256) void fill_kernel(
    const int* __restrict__ src, const int* __restrict__ dst,
    int* __restrict__ fillptr, int* __restrict__ col, int* __restrict__ eid, int E)
{
    int e = blockIdx.x * 256 + threadIdx.x;
    if (e >= E) return;
    int d = dst[e];
    int p = atomicAdd(&fillptr[d], 1);
    col[p] = src[e];
    eid[p] = e;
}

// ====== edge_attr scatter-mean via CSR -> hi/lo bf16 [N x 32] (K-padded) ===
__global__ __launch_bounds__(64) void nef_csr_kernel(
    const float* __restrict__ ea, const int* __restrict__ rowptr,
    const int* __restrict__ eid,
    unsigned short* __restrict__ nefH, unsigned short* __restrict__ nefL, int N)
{
    int n = blockIdx.x;
    int t = threadIdx.x;
    int f = t & 15, g = t >> 4;
    int base = rowptr[n], end = rowptr[n + 1];
    int deg = end - base - 1;
    float acc = 0.0f;
    for (int j = base + 1 + g; j < end; j += 4) {
        int e = eid[j];
        acc += ea[(size_t)e * 16 + f];
    }
    acc += __shfl_down(acc, 32, 64);
    acc += __shfl_down(acc, 16, 64);
    if (t < 16) {
        float v = acc / fmaxf((float)deg, 1.0f);
        unsigned short h, l;
        split_hilo(v, h, l);
        nefH[(size_t)n * 32 + t] = h;
        nefL[(size_t)n * 32 + t] = l;
    } else if (t < 32) {
        nefH[(size_t)n * 32 + t] = 0;
        nefL[(size_t)n * 32 + t] = 0;
    }
}

// ============ convert f32 -> hi/lo bf16 (2 elems per thread) ===============
__global__ __launch_bounds__(256) void conv_hilo_kernel(
    const float* __restrict__ X,
    unsigned short* __restrict__ H, unsigned short* __restrict__ L, int total)
{
    int base = (blockIdx.x * 256 + threadIdx.x) * 2;
    if (base >= total) return;
    #pragma unroll
    for (int i = 0; i < 2; i++) {
        unsigned short h, l;
        split_hilo(X[base + i], h, l);
        H[base + i] = h;
        L[base + i] = l;
    }
}

// ============ pack weights [K x 256] -> B-fragment order, hi/lo ============
__global__ __launch_bounds__(256) void pack_w_kernel(
    const float* __restrict__ W, int K, int KP,
    unsigned short* __restrict__ Ph, unsigned short* __restrict__ Pl)
{
    int idx = blockIdx.x * 256 + threadIdx.x;
    if (idx >= KP * 256) return;
    int tile = idx >> 9, w = idx & 511, lane = w >> 3, j = w & 7;
    int nk = KP >> 5;
    int ctile = tile / nk, t = tile % nk;
    int k = t * 32 + ((lane >> 4) << 3) + j;
    int n = (ctile << 4) + (lane & 15);
    float v = (k < K) ? W[(size_t)k * 256 + n] : 0.0f;
    unsigned short h, l;
    split_hilo(v, h, l);
    Ph[idx] = h;
    Pl[idx] = l;
}

// ===================== MFMA bf16x3 GEMM ====================================
// C[N x 256] = A[N x KP] @ W[KP x 256] (+bias). Block: 64 rows x 128 cols
// (grid.y=2), 4 waves (wave = 16 rows), 8 col-tiles. FUSE_ATT: per-row
// per-head attention dots from accumulators; head 2y+hl is fully contained
// in block y (64 cols = 4 tiles) -> direct store, no atomics.
template <int KSTEPS, bool HILO, bool FUSE_ATT>
__global__ __launch_bounds__(256) void mfma_gemm_kernel(
    const unsigned short* __restrict__ Ah, const unsigned short* __restrict__ Al,
    int lda,
    const unsigned short* __restrict__ Ph, const unsigned short* __restrict__ Pl,
    const float* __restrict__ bias,
    float* __restrict__ Cf,
    unsigned short* __restrict__ Ch, unsigned short* __restrict__ Cl,
    int ldc, int col_off, int Nrows,
    const float* __restrict__ att_src, const float* __restrict__ att_dst,
    float* __restrict__ a_srcO, float* __restrict__ a_dstO)
{
    int tid = threadIdx.x;
    int wave = tid >> 6, lane = tid & 63;
    int quad = lane >> 4, m16 = lane & 15;
    int row = blockIdx.x * 64 + wave * 16 + m16;
    bool rowok = row < Nrows;
    int ctile0 = blockIdx.y * 8;

    f32x4 acc[8] = {};
    const unsigned short* arh = Ah + (size_t)row * lda;
    const unsigned short* arl = Al + (size_t)row * lda;

    for (int t = 0; t < KSTEPS; t++) {
        int k = t * 32 + quad * 8;
        bf16x8 a_h = {}, a_l = {};
        if (rowok) {
            a_h = *(const bf16x8*)(arh + k);
            a_l = *(const bf16x8*)(arl + k);
        }
        #pragma unroll
        for (int c = 0; c < 8; c++) {
            size_t wb = ((size_t)((ctile0 + c) * KSTEPS + t)) * 512 + lane * 8;
            bf16x8 b_h = *(const bf16x8*)(Ph + wb);
            bf16x8 b_l = *(const bf16x8*)(Pl + wb);
            acc[c] = __builtin_amdgcn_mfma_f32_16x16x32_bf16(a_h, b_h, acc[c], 0, 0, 0);
            acc[c] = __builtin_amdgcn_mfma_f32_16x16x32_bf16(a_l, b_h, acc[c], 0, 0, 0);
            acc[c] = __builtin_amdgcn_mfma_f32_16x16x32_bf16(a_h, b_l, acc[c], 0, 0, 0);
        }
    }

    // main epilogue: D[row = quad*4 + r][col = m16] within each 16x16 tile
    #pragma unroll
    for (int c = 0; c < 8; c++) {
        int ocol = (ctile0 + c) * 16 + m16;
        float bv = bias ? bias[ocol] : 0.0f;
        #pragma unroll
        for (int r = 0; r < 4; r++) {
            int orow = blockIdx.x * 64 + wave * 16 + quad * 4 + r;
            if (orow >= Nrows) continue;
            float v = acc[c][r] + bv;
            size_t oidx = (size_t)orow * ldc + col_off + ocol;
            if (HILO) {
                unsigned short h, l;
                split_hilo(v, h, l);
                Ch[oidx] = h;
                Cl[oidx] = l;
            } else {
                Cf[oidx] = v;
            }
        }
    }

    if (FUSE_ATT) {
        // per-row (r), per-local-head (hl=c>>2) attention dot partials;
        // head hl spans tiles 4*hl..4*hl+3 (fully inside this block)
        float ps[4][2] = {}, pd[4][2] = {};
        #pragma unroll
        for (int c = 0; c < 8; c++) {
            int ocol = (ctile0 + c) * 16 + m16;
            float asv = att_src[ocol];
            float adv = att_dst[ocol];
            int hl = c >> 2;
            #pragma unroll
            for (int r = 0; r < 4; r++) {
                ps[r][hl] += acc[c][r] * asv;
                pd[r][hl] += acc[c][r] * adv;
            }
        }
        #pragma unroll
        for (int r = 0; r < 4; r++) {
            #pragma unroll
            for (int hl = 0; hl < 2; hl++) {
                float s = ps[r][hl], d = pd[r][hl];
                #pragma unroll
                for (int o = 8; o > 0; o >>= 1) {
                    s += __shfl_down(s, o, 64);
                    d += __shfl_down(d, o, 64);
                }
                if (m16 == 0) {
                    int orow = blockIdx.x * 64 + wave * 16 + quad * 4 + r;
                    if (orow < Nrows) {
                        int gh = blockIdx.y * 2 + hl;
                        a_srcO[orow * 4 + gh] = s;
                        a_dstO[orow * 4 + gh] = d;
                    }
                }
            }
        }
    }
}

// ===== CSR aggregation: single-pass softmax + weighted sum + bias + ELU ====
// one block per dst node; 4 groups (waves) x unroll-2 = 8 edges in flight;
// lane covers 4 consecutive cols via float4; unnormalized accumulation with
// fused denominator (no max-subtract: logits O(10), exp safe in f32).
__global__ __launch_bounds__(256) void gat_agg_csr_kernel(
    const float* __restrict__ xh,
    const int* __restrict__ rowptr, const int* __restrict__ col,
    const float* __restrict__ a_src, const float* __restrict__ a_dst,
    const float* __restrict__ bias,
    unsigned short* __restrict__ outH, unsigned short* __restrict__ outL, int N)
{
    __shared__ float red[1024];
    __shared__ float dpart[4][HEADS];
    int n = blockIdx.x;
    int t = threadIdx.x;
    int g = t >> 6, c = t & 63;
    int h = c >> 4;
    int base = rowptr[n], end = rowptr[n + 1];
    float adst = a_dst[n * 4 + h];
    const float* xcol = xh + (c << 2);

    float4 acc = {0.0f, 0.0f, 0.0f, 0.0f};
    float den = 0.0f;
    int j = base + 2 * g;
    for (; j + 1 < end; j += 8) {
        int s0 = col[j], s1 = col[j + 1];
        float l0 = a_src[s0 * 4 + h] + adst;
        float l1 = a_src[s1 * 4 + h] + adst;
        l0 = (l0 > 0.0f) ? l0 : 0.2f * l0;
        l1 = (l1 > 0.0f) ? l1 : 0.2f * l1;
        float w0 = __expf(l0), w1 = __expf(l1);
        float4 x0 = *(const float4*)(xcol + (size_t)s0 * 256);
        float4 x1 = *(const float4*)(xcol + (size_t)s1 * 256);
        den += w0 + w1;
        acc.x += w0 * x0.x + w1 * x1.x;
        acc.y += w0 * x0.y + w1 * x1.y;
        acc.z += w0 * x0.z + w1 * x1.z;
        acc.w += w0 * x0.w + w1 * x1.w;
    }
    if (j < end) {
        int s0 = col[j];
        float l0 = a_src[s0 * 4 + h] + adst;
        l0 = (l0 > 0.0f) ? l0 : 0.2f * l0;
        float w0 = __expf(l0);
        float4 x0 = *(const float4*)(xcol + (size_t)s0 * 256);
        den += w0;
        acc.x += w0 * x0.x;
        acc.y += w0 * x0.y;
        acc.z += w0 * x0.z;
        acc.w += w0 * x0.w;
    }
    *(float4*)(&red[g * 256 + (c << 2)]) = acc;
    if ((c & 15) == 0) dpart[g][h] = den;
    __syncthreads();

    // combine groups + normalize + bias + ELU + hi/lo split; thread t = col t
    int th = t >> 6;
    float dsum = dpart[0][th] + dpart[1][th] + dpart[2][th] + dpart[3][th];
    float v = (red[t] + red[256 + t] + red[512 + t] + red[768 + t]) / dsum + bias[t];
    v = (v > 0.0f) ? v : (__expf(v) - 1.0f);
    unsigned short hh, ll;
    split_hilo(v, hh, ll);
    outH[(size_t)n * 256 + t] = hh;
    outL[(size_t)n * 256 + t] = ll;
}

// ===========================================================================

extern "C" void kernel_launch(void* const* d_in, const int* in_sizes, int n_in,
                              void* d_out, int out_size, void* d_ws, size_t ws_size,
                              hipStream_t stream)
{
    const float* node_feats = (const float*)d_in[0];
    const float* edge_attr  = (const float*)d_in[1];
    const float* Wnp = (const float*)d_in[2];
    const float* bnp = (const float*)d_in[3];
    const float* Wep = (const float*)d_in[4];
    const float* bep = (const float*)d_in[5];
    const float* Wg1 = (const float*)d_in[6];
    const float* as1 = (const float*)d_in[7];
    const float* ad1 = (const float*)d_in[8];
    const float* bg1 = (const float*)d_in[9];
    const float* Wg2 = (const float*)d_in[10];
    const float* as2 = (const float*)d_in[11];
    const float* ad2 = (const float*)d_in[12];
    const float* bg2 = (const float*)d_in[13];
    const float* Wo  = (const float*)d_in[14];
    const float* bo  = (const float*)d_in[15];
    const int*   ei  = (const int*)d_in[16];

    const int N = in_sizes[0] / 128;   // 50000
    const int E = in_sizes[16] / 2;    // 800000
    const int* src = ei;
    const int* dst = ei + E;
    const int nchunk = (N + 255) / 256;
    const int EN = E + N;

    typedef unsigned short u16;

    // ---- workspace layout (256B-aligned regions) ----
    char* base = (char*)d_ws;
    size_t off = 0;
    auto alloc = [&](size_t bytes) -> char* {
        char* p = base + off;
        off += (bytes + 255) & ~(size_t)255;
        return p;
    };
    float* xh = (float*)alloc((size_t)N * 256 * 4);        // f32 xh; hosts nf/nef aliases
    u16* x2H  = (u16*)alloc((size_t)N * 512 * 2);          // hosts x3H/x3L after GEMM3
    u16* x2L  = (u16*)alloc((size_t)N * 512 * 2);          // hosts x4H/x4L after GEMM3
    float* a_src = (float*)alloc((size_t)N * 4 * 4);
    float* a_dst = (float*)alloc((size_t)N * 4 * 4);
    u16* PnpH = (u16*)alloc(128 * 256 * 2);
    u16* PnpL = (u16*)alloc(128 * 256 * 2);
    u16* PepH = (u16*)alloc(32 * 256 * 2);
    u16* PepL = (u16*)alloc(32 * 256 * 2);
    u16* Pg1H = (u16*)alloc(512 * 256 * 2);
    u16* Pg1L = (u16*)alloc(512 * 256 * 2);
    u16* Pg2H = (u16*)alloc(256 * 256 * 2);
    u16* Pg2L = (u16*)alloc(256 * 256 * 2);
    u16* PoH  = (u16*)alloc(256 * 256 * 2);
    u16* PoL  = (u16*)alloc(256 * 256 * 2);
    int* cnt       = (int*)alloc((size_t)N * 4);
    int* rowptr    = (int*)alloc((size_t)(N + 1) * 4);
    int* fillptr   = (int*)alloc((size_t)N * 4);
    int* chunk_sum = (int*)alloc((size_t)nchunk * 4);
    int* chunk_off = (int*)alloc((size_t)nchunk * 4);
    int* colv      = (int*)alloc((size_t)EN * 4);
    int* eid       = (int*)alloc((size_t)EN * 4);

    // aliases inside xh region (dead before GEMM3 writes xh)
    u16* nfH  = (u16*)xh;
    u16* nfL  = nfH + (size_t)N * 128;
    u16* nefH = nfL + (size_t)N * 128;
    u16* nefL = nefH + (size_t)N * 32;
    // aliases inside x2 regions (x2 dead after GEMM3)
    u16* x3H = x2H;
    u16* x3L = x2H + (size_t)N * 256;
    u16* x4H = x2L;
    u16* x4L = x2L + (size_t)N * 256;

    float* out = (float*)d_out;
    dim3 ggrid((N + 63) / 64, 2);

    // ---- CSR build ----
    hipMemsetAsync(cnt, 0, (size_t)N * sizeof(int), stream);
    count_kernel<<<(E + 255) / 256, 256, 0, stream>>>(dst, cnt, E);
    scan1_kernel<<<nchunk, 256, 0, stream>>>(cnt, chunk_sum, N);
    scan2_kernel<<<1, 1, 0, stream>>>(chunk_sum, chunk_off, nchunk);
    scan3_kernel<<<nchunk, 256, 0, stream>>>(cnt, chunk_off, rowptr, fillptr, colv, eid, N);
    fill_kernel<<<(E + 255) / 256, 256, 0, stream>>>(src, dst, fillptr, colv, eid, E);

    // ---- input conversions + weight packing ----
    nef_csr_kernel<<<N, 64, 0, stream>>>(edge_attr, rowptr, eid, nefH, nefL, N);
    conv_hilo_kernel<<<((N * 128) / 2 + 255) / 256, 256, 0, stream>>>(
        node_feats, nfH, nfL, N * 128);
    pack_w_kernel<<<(128 * 256 + 255) / 256, 256, 0, stream>>>(Wnp, 128, 128, PnpH, PnpL);
    pack_w_kernel<<<(32 * 256 + 255) / 256, 256, 0, stream>>>(Wep, 16, 32, PepH, PepL);
    pack_w_kernel<<<(512 * 256 + 255) / 256, 256, 0, stream>>>(Wg1, 512, 512, Pg1H, Pg1L);
    pack_w_kernel<<<(256 * 256 + 255) / 256, 256, 0, stream>>>(Wg2, 256, 256, Pg2H, Pg2L);
    pack_w_kernel<<<(256 * 256 + 255) / 256, 256, 0, stream>>>(Wo, 256, 256, PoH, PoL);

    // ---- x2 = [ nf@Wnp + bnp | nef@Wep + bep ] -> x2H/x2L [N x 512] ----
    mfma_gemm_kernel<4, true, false><<<ggrid, 256, 0, stream>>>(
        nfH, nfL, 128, PnpH, PnpL, bnp, nullptr, x2H, x2L, 512, 0, N,
        nullptr, nullptr, nullptr, nullptr);
    mfma_gemm_kernel<1, true, false><<<ggrid, 256, 0, stream>>>(
        nefH, nefL, 32, PepH, PepL, bep, nullptr, x2H, x2L, 512, 256, N,
        nullptr, nullptr, nullptr, nullptr);

    // ---- GAT layer 1: GEMM (+fused att dots) -> agg ----
    mfma_gemm_kernel<16, false, true><<<ggrid, 256, 0, stream>>>(
        x2H, x2L, 512, Pg1H, Pg1L, nullptr, xh, nullptr, nullptr, 256, 0, N,
        as1, ad1, a_src, a_dst);
    gat_agg_csr_kernel<<<N, 256, 0, stream>>>(
        xh, rowptr, colv, a_src, a_dst, bg1, x3H, x3L, N);

    // ---- GAT layer 2 ----
    mfma_gemm_kernel<8, false, true><<<ggrid, 256, 0, stream>>>(
        x3H, x3L, 256, Pg2H, Pg2L, nullptr, xh, nullptr, nullptr, 256, 0, N,
        as2, ad2, a_src, a_dst);
    gat_agg_csr_kernel<<<N, 256, 0, stream>>>(
        xh, rowptr, colv, a_src, a_dst, bg2, x4H, x4L, N);

    // ---- out = x4 @ Wo + bo -> d_out (f32) ----
    mfma_gemm_kernel<8, false, false><<<ggrid, 256, 0, stream>>>(
        x4H, x4L, 256, PoH, PoL, bo, out, nullptr, nullptr, 256, 0, N,
        nullptr, nullptr, nullptr, nullptr);
}